// Round 2
// baseline (313.821 us; speedup 1.0000x reference)
//
#include <hip/hip_runtime.h>
#include <math.h>

#define Bv  4
#define Cv  64
#define DCv 32
#define Fv  128
#define Tv  512
#define FT  (Fv * Tv)

// Swizzled Q layout in LDS (K1): column-owner dim tt (0..255), element dim k (0..31).
__device__ __forceinline__ int qoff4(int tt, int j) { return tt * 32 + ((j ^ (tt & 7)) << 2); }

// ---------------------------------------------------------------------------
// K1: conv1 + BN + PReLU -> Q (workspace), plus per-half partial M = Q Q^T
// grid: (b,f,half) = 1024 blocks x 256 threads. 37 KB LDS -> 4 blocks/CU.
// ---------------------------------------------------------------------------
__global__ __launch_bounds__(256, 4)
void k1_conv_q_m(const float* __restrict__ inp,
                 const float* __restrict__ w1, const float* __restrict__ b1,
                 const float* __restrict__ g1, const float* __restrict__ be1,
                 const float* __restrict__ m1, const float* __restrict__ v1,
                 const float* __restrict__ a1,
                 float* __restrict__ Qws, float* __restrict__ Mws)
{
    __shared__ __align__(16) float sQ[256 * DCv];  // 32 KB
    __shared__ __align__(16) float sM[DCv * DCv];  // 4 KB
    __shared__ float sS1[DCv], sT1[DCv];

    const int tid  = threadIdx.x;
    const int bid  = blockIdx.x;
    const int half = bid & 1;
    const int bf   = bid >> 1;
    const int b    = bf >> 7;
    const int f    = bf & 127;

    if (tid < DCv) {
        float s = g1[tid] / sqrtf(v1[tid] + 1e-5f);
        sS1[tid] = s;
        sT1[tid] = (b1[tid] - m1[tid]) * s + be1[tid];
    }
    sM[tid] = 0.f; sM[tid + 256] = 0.f; sM[tid + 512] = 0.f; sM[tid + 768] = 0.f;
    const float alpha1 = a1[0];
    __syncthreads();

    const int t = half * 256 + tid;

    // conv1 for column t
    float acc[DCv];
    #pragma unroll
    for (int c = 0; c < DCv; ++c) acc[c] = 0.f;
    #pragma unroll
    for (int hc = 0; hc < 2; ++hc) {
        float x[32];
        const float* px = inp + ((size_t)(b * Cv + hc * 32) * Fv + f) * Tv + t;
        #pragma unroll
        for (int i = 0; i < 32; ++i) x[i] = px[i * FT];
        #pragma unroll 4
        for (int c = 0; c < DCv; ++c) {
            const float* wr = w1 + c * Cv + hc * 32;  // uniform -> scalar loads
            float a = acc[c];
            #pragma unroll
            for (int i = 0; i < 32; ++i) a = fmaf(wr[i], x[i], a);
            acc[c] = a;
        }
    }
    float* qg = Qws + ((size_t)bf * Tv + t) * DCv;
    #pragma unroll
    for (int j = 0; j < 8; ++j) {
        float z0 = fmaf(acc[4*j+0], sS1[4*j+0], sT1[4*j+0]);
        float z1 = fmaf(acc[4*j+1], sS1[4*j+1], sT1[4*j+1]);
        float z2 = fmaf(acc[4*j+2], sS1[4*j+2], sT1[4*j+2]);
        float z3 = fmaf(acc[4*j+3], sS1[4*j+3], sT1[4*j+3]);
        float4 v;
        v.x = z0 >= 0.f ? z0 : alpha1 * z0;
        v.y = z1 >= 0.f ? z1 : alpha1 * z1;
        v.z = z2 >= 0.f ? z2 : alpha1 * z2;
        v.w = z3 >= 0.f ? z3 : alpha1 * z3;
        *(float4*)&sQ[qoff4(tid, j)] = v;
        *(float4*)&qg[j * 4] = v;
    }
    __syncthreads();

    // partial M over this half's 256 columns (raw sums; scaled in K2)
    {
        const int w = tid >> 6, l = tid & 63;
        const int c1b = l >> 3;   // 4-row block
        const int c2b = l & 7;    // 4-col block
        float4 r0 = {0,0,0,0}, r1 = {0,0,0,0}, r2 = {0,0,0,0}, r3 = {0,0,0,0};
        const int kbase = w * 64;
        for (int i = 0; i < 64; ++i) {
            const int k = kbase + i;
            const float4 qa = *(const float4*)&sQ[qoff4(k, c1b)];
            const float4 qb = *(const float4*)&sQ[qoff4(k, c2b)];
            r0.x = fmaf(qa.x, qb.x, r0.x); r0.y = fmaf(qa.x, qb.y, r0.y);
            r0.z = fmaf(qa.x, qb.z, r0.z); r0.w = fmaf(qa.x, qb.w, r0.w);
            r1.x = fmaf(qa.y, qb.x, r1.x); r1.y = fmaf(qa.y, qb.y, r1.y);
            r1.z = fmaf(qa.y, qb.z, r1.z); r1.w = fmaf(qa.y, qb.w, r1.w);
            r2.x = fmaf(qa.z, qb.x, r2.x); r2.y = fmaf(qa.z, qb.y, r2.y);
            r2.z = fmaf(qa.z, qb.z, r2.z); r2.w = fmaf(qa.z, qb.w, r2.w);
            r3.x = fmaf(qa.w, qb.x, r3.x); r3.y = fmaf(qa.w, qb.y, r3.y);
            r3.z = fmaf(qa.w, qb.z, r3.z); r3.w = fmaf(qa.w, qb.w, r3.w);
        }
        float* m0 = &sM[(c1b * 4 + 0) * DCv + c2b * 4];
        float* m1r = &sM[(c1b * 4 + 1) * DCv + c2b * 4];
        float* m2r = &sM[(c1b * 4 + 2) * DCv + c2b * 4];
        float* m3r = &sM[(c1b * 4 + 3) * DCv + c2b * 4];
        atomicAdd(m0 + 0, r0.x); atomicAdd(m0 + 1, r0.y);
        atomicAdd(m0 + 2, r0.z); atomicAdd(m0 + 3, r0.w);
        atomicAdd(m1r + 0, r1.x); atomicAdd(m1r + 1, r1.y);
        atomicAdd(m1r + 2, r1.z); atomicAdd(m1r + 3, r1.w);
        atomicAdd(m2r + 0, r2.x); atomicAdd(m2r + 1, r2.y);
        atomicAdd(m2r + 2, r2.z); atomicAdd(m2r + 3, r2.w);
        atomicAdd(m3r + 0, r3.x); atomicAdd(m3r + 1, r3.y);
        atomicAdd(m3r + 2, r3.z); atomicAdd(m3r + 3, r3.w);
    }
    __syncthreads();

    float4 mv = *(const float4*)&sM[tid * 4];
    *(float4*)&Mws[(size_t)bid * 1024 + tid * 4] = mv;
}

// ---------------------------------------------------------------------------
// K2: M = sum(Mpart)/sqrt(32); O = M q; mask; softmax over t; conv2 + residual
// grid: (b,f) = 512 blocks x 512 threads. ~6 KB LDS.
// ---------------------------------------------------------------------------
__global__ __launch_bounds__(512, 4)
void k2_attn_conv_out(const float* __restrict__ inp,
                      const float* __restrict__ Qws, const float* __restrict__ Mws,
                      const float* __restrict__ wp, const float* __restrict__ bp,
                      const float* __restrict__ g2, const float* __restrict__ be2,
                      const float* __restrict__ m2, const float* __restrict__ v2,
                      const float* __restrict__ a2,
                      float* __restrict__ out)
{
    __shared__ __align__(16) float sM[DCv * DCv];  // 4 KB
    __shared__ float sS2[Cv], sT2[Cv];
    __shared__ float sWred[8 * DCv];
    __shared__ float sMx[DCv], sRZ[DCv];

    const int tid = threadIdx.x;
    const int bf  = blockIdx.x;
    const int b   = bf >> 7;
    const int f   = bf & 127;

    const float INV = 0.17677669529663687f;  // 1/sqrt(32)
    const float* mp0 = Mws + (size_t)bf * 2048;
    const float* mp1 = mp0 + 1024;
    sM[tid]       = (mp0[tid]       + mp1[tid])       * INV;
    sM[tid + 512] = (mp0[tid + 512] + mp1[tid + 512]) * INV;
    if (tid < Cv) {
        float s = g2[tid] / sqrtf(v2[tid] + 1e-5f);
        sS2[tid] = s;
        sT2[tid] = (bp[tid] - m2[tid]) * s + be2[tid];
    }
    const float alpha2 = a2[0];
    __syncthreads();

    const int t = tid;
    const int l = tid & 63, w = tid >> 6;

    // q column from workspace (contiguous 128 B per thread)
    float q[DCv];
    const float* qg = Qws + ((size_t)bf * Tv + t) * DCv;
    #pragma unroll
    for (int j = 0; j < 8; ++j) {
        float4 v = *(const float4*)&qg[j * 4];
        q[4*j] = v.x; q[4*j+1] = v.y; q[4*j+2] = v.z; q[4*j+3] = v.w;
    }

    // O = M q (M rows broadcast from LDS)
    float O[DCv];
    #pragma unroll 2
    for (int j = 0; j < 8; ++j) {
        const float4* M0 = (const float4*)&sM[(4*j+0) * DCv];
        const float4* M1 = (const float4*)&sM[(4*j+1) * DCv];
        const float4* M2 = (const float4*)&sM[(4*j+2) * DCv];
        const float4* M3 = (const float4*)&sM[(4*j+3) * DCv];
        float d0 = 0.f, d1 = 0.f, d2 = 0.f, d3 = 0.f;
        #pragma unroll
        for (int kk = 0; kk < 8; ++kk) {
            float4 a = M0[kk], bq = M1[kk], c = M2[kk], d = M3[kk];
            d0 = fmaf(a.x, q[4*kk], d0); d0 = fmaf(a.y, q[4*kk+1], d0);
            d0 = fmaf(a.z, q[4*kk+2], d0); d0 = fmaf(a.w, q[4*kk+3], d0);
            d1 = fmaf(bq.x, q[4*kk], d1); d1 = fmaf(bq.y, q[4*kk+1], d1);
            d1 = fmaf(bq.z, q[4*kk+2], d1); d1 = fmaf(bq.w, q[4*kk+3], d1);
            d2 = fmaf(c.x, q[4*kk], d2); d2 = fmaf(c.y, q[4*kk+1], d2);
            d2 = fmaf(c.z, q[4*kk+2], d2); d2 = fmaf(c.w, q[4*kk+3], d2);
            d3 = fmaf(d.x, q[4*kk], d3); d3 = fmaf(d.y, q[4*kk+1], d3);
            d3 = fmaf(d.z, q[4*kk+2], d3); d3 = fmaf(d.w, q[4*kk+3], d3);
        }
        O[4*j] = d0; O[4*j+1] = d1; O[4*j+2] = d2; O[4*j+3] = d3;
    }

    // causal mask: valid iff t < f + 385
    int limit = f + (Tv - Fv + 1);
    if (limit > Tv) limit = Tv;
    const bool valid = t < limit;

    // softmax pass 1: per-channel max over t (wave butterfly + cross-wave LDS)
    {
        float mine = -INFINITY;
        #pragma unroll
        for (int c = 0; c < DCv; ++c) {
            float m = valid ? O[c] : -INFINITY;
            #pragma unroll
            for (int s = 1; s < 64; s <<= 1) m = fmaxf(m, __shfl_xor(m, s));
            mine = ((l & 31) == c) ? m : mine;
        }
        if (l < DCv) sWred[w * DCv + l] = mine;
    }
    __syncthreads();
    if (tid < DCv) {
        float mx = sWred[tid];
        #pragma unroll
        for (int ww = 1; ww < 8; ++ww) mx = fmaxf(mx, sWred[ww * DCv + tid]);
        sMx[tid] = mx;
    }
    __syncthreads();

    // softmax pass 2: exp + per-channel sum
    float e[DCv];
    #pragma unroll
    for (int c = 0; c < DCv; ++c) e[c] = valid ? __expf(O[c] - sMx[c]) : 0.f;
    {
        float mine = 0.f;
        #pragma unroll
        for (int c = 0; c < DCv; ++c) {
            float s2 = e[c];
            #pragma unroll
            for (int s = 1; s < 64; s <<= 1) s2 += __shfl_xor(s2, s);
            mine = ((l & 31) == c) ? s2 : mine;
        }
        if (l < DCv) sWred[w * DCv + l] = mine;
    }
    __syncthreads();
    if (tid < DCv) {
        float z = sWred[tid];
        #pragma unroll
        for (int ww = 1; ww < 8; ++ww) z += sWred[ww * DCv + tid];
        sRZ[tid] = 1.f / z;
    }
    __syncthreads();
    #pragma unroll
    for (int c = 0; c < DCv; ++c) e[c] *= sRZ[c];

    // conv2 + BN + PReLU + residual
    #pragma unroll
    for (int half = 0; half < 2; ++half) {
        const float* pin = inp + ((size_t)(b * Cv + half * 32) * Fv + f) * Tv + t;
        float*       pot = out + ((size_t)(b * Cv + half * 32) * Fv + f) * Tv + t;
        float rin[32];
        #pragma unroll
        for (int i = 0; i < 32; ++i) rin[i] = pin[i * FT];
        #pragma unroll 4
        for (int oo = 0; oo < 32; ++oo) {
            const int o = half * 32 + oo;
            const float* wr = wp + o * DCv;  // uniform -> scalar loads
            float a = 0.f;
            #pragma unroll
            for (int c2 = 0; c2 < DCv; ++c2) a = fmaf(wr[c2], e[c2], a);
            float z = fmaf(a, sS2[o], sT2[o]);
            z = z >= 0.f ? z : alpha2 * z;
            pot[oo * FT] = z + rin[oo];
        }
    }
}

extern "C" void kernel_launch(void* const* d_in, const int* in_sizes, int n_in,
                              void* d_out, int out_size, void* d_ws, size_t ws_size,
                              hipStream_t stream) {
    const float* inp = (const float*)d_in[0];
    const float* w1  = (const float*)d_in[1];
    const float* b1  = (const float*)d_in[2];
    const float* g1  = (const float*)d_in[3];
    const float* be1 = (const float*)d_in[4];
    const float* m1  = (const float*)d_in[5];
    const float* v1  = (const float*)d_in[6];
    const float* a1  = (const float*)d_in[7];
    const float* wp  = (const float*)d_in[8];
    const float* bp  = (const float*)d_in[9];
    const float* g2  = (const float*)d_in[10];
    const float* be2 = (const float*)d_in[11];
    const float* m2  = (const float*)d_in[12];
    const float* v2  = (const float*)d_in[13];
    const float* a2  = (const float*)d_in[14];

    float* Qws = (float*)d_ws;                                  // 4*128*512*32 f32 = 33.6 MB
    float* Mws = Qws + (size_t)Bv * Fv * Tv * DCv;              // 1024*1024 f32 = 4.2 MB

    k1_conv_q_m<<<dim3(Bv * Fv * 2), dim3(256), 0, stream>>>(
        inp, w1, b1, g1, be1, m1, v1, a1, Qws, Mws);
    k2_attn_conv_out<<<dim3(Bv * Fv), dim3(512), 0, stream>>>(
        inp, Qws, Mws, wp, bp, g2, be2, m2, v2, a2, (float*)d_out);
}

// Round 3
// 164.348 us; speedup vs baseline: 1.9095x; 1.9095x over previous
//
#include <hip/hip_runtime.h>
#include <math.h>

#define Bv  4
#define Cv  64
#define DCv 32
#define Fv  128
#define Tv  512
#define FT  (Fv * Tv)

// Swizzled Q layout in LDS (K1): column-owner dim tt (0..255), element dim k (0..31).
__device__ __forceinline__ int qoff4(int tt, int j) { return tt * 32 + ((j ^ (tt & 7)) << 2); }

// ---------------------------------------------------------------------------
// K1: conv1 + BN + PReLU -> Q (workspace), plus per-half partial M = Q Q^T
// grid: (b,f,half) = 1024 blocks x 256 threads. 37 KB LDS -> 4 blocks/CU.
// (256,4): 4 waves/EU -> 4 blocks/CU -> 128-VGPR cap; conv working set fits
// (round-1 fused ran same code at 68 VGPR).
// ---------------------------------------------------------------------------
__global__ __launch_bounds__(256, 4)
void k1_conv_q_m(const float* __restrict__ inp,
                 const float* __restrict__ w1, const float* __restrict__ b1,
                 const float* __restrict__ g1, const float* __restrict__ be1,
                 const float* __restrict__ m1, const float* __restrict__ v1,
                 const float* __restrict__ a1,
                 float* __restrict__ Qws, float* __restrict__ Mws)
{
    __shared__ __align__(16) float sQ[256 * DCv];  // 32 KB
    __shared__ __align__(16) float sM[DCv * DCv];  // 4 KB
    __shared__ float sS1[DCv], sT1[DCv];

    const int tid  = threadIdx.x;
    const int bid  = blockIdx.x;
    const int half = bid & 1;
    const int bf   = bid >> 1;
    const int b    = bf >> 7;
    const int f    = bf & 127;

    if (tid < DCv) {
        float s = g1[tid] / sqrtf(v1[tid] + 1e-5f);
        sS1[tid] = s;
        sT1[tid] = (b1[tid] - m1[tid]) * s + be1[tid];
    }
    sM[tid] = 0.f; sM[tid + 256] = 0.f; sM[tid + 512] = 0.f; sM[tid + 768] = 0.f;
    const float alpha1 = a1[0];
    __syncthreads();

    const int t = half * 256 + tid;

    // conv1 for column t
    float acc[DCv];
    #pragma unroll
    for (int c = 0; c < DCv; ++c) acc[c] = 0.f;
    #pragma unroll
    for (int hc = 0; hc < 2; ++hc) {
        float x[32];
        const float* px = inp + ((size_t)(b * Cv + hc * 32) * Fv + f) * Tv + t;
        #pragma unroll
        for (int i = 0; i < 32; ++i) x[i] = px[i * FT];
        #pragma unroll 4
        for (int c = 0; c < DCv; ++c) {
            const float* wr = w1 + c * Cv + hc * 32;  // uniform -> scalar loads
            float a = acc[c];
            #pragma unroll
            for (int i = 0; i < 32; ++i) a = fmaf(wr[i], x[i], a);
            acc[c] = a;
        }
    }
    float* qg = Qws + ((size_t)bf * Tv + t) * DCv;
    #pragma unroll
    for (int j = 0; j < 8; ++j) {
        float z0 = fmaf(acc[4*j+0], sS1[4*j+0], sT1[4*j+0]);
        float z1 = fmaf(acc[4*j+1], sS1[4*j+1], sT1[4*j+1]);
        float z2 = fmaf(acc[4*j+2], sS1[4*j+2], sT1[4*j+2]);
        float z3 = fmaf(acc[4*j+3], sS1[4*j+3], sT1[4*j+3]);
        float4 v;
        v.x = z0 >= 0.f ? z0 : alpha1 * z0;
        v.y = z1 >= 0.f ? z1 : alpha1 * z1;
        v.z = z2 >= 0.f ? z2 : alpha1 * z2;
        v.w = z3 >= 0.f ? z3 : alpha1 * z3;
        *(float4*)&sQ[qoff4(tid, j)] = v;
        *(float4*)&qg[j * 4] = v;
    }
    __syncthreads();

    // partial M over this half's 256 columns (raw sums; scaled in K2)
    {
        const int w = tid >> 6, l = tid & 63;
        const int c1b = l >> 3;   // 4-row block
        const int c2b = l & 7;    // 4-col block
        float4 r0 = {0,0,0,0}, r1 = {0,0,0,0}, r2 = {0,0,0,0}, r3 = {0,0,0,0};
        const int kbase = w * 64;
        for (int i = 0; i < 64; ++i) {
            const int k = kbase + i;
            const float4 qa = *(const float4*)&sQ[qoff4(k, c1b)];
            const float4 qb = *(const float4*)&sQ[qoff4(k, c2b)];
            r0.x = fmaf(qa.x, qb.x, r0.x); r0.y = fmaf(qa.x, qb.y, r0.y);
            r0.z = fmaf(qa.x, qb.z, r0.z); r0.w = fmaf(qa.x, qb.w, r0.w);
            r1.x = fmaf(qa.y, qb.x, r1.x); r1.y = fmaf(qa.y, qb.y, r1.y);
            r1.z = fmaf(qa.y, qb.z, r1.z); r1.w = fmaf(qa.y, qb.w, r1.w);
            r2.x = fmaf(qa.z, qb.x, r2.x); r2.y = fmaf(qa.z, qb.y, r2.y);
            r2.z = fmaf(qa.z, qb.z, r2.z); r2.w = fmaf(qa.z, qb.w, r2.w);
            r3.x = fmaf(qa.w, qb.x, r3.x); r3.y = fmaf(qa.w, qb.y, r3.y);
            r3.z = fmaf(qa.w, qb.z, r3.z); r3.w = fmaf(qa.w, qb.w, r3.w);
        }
        float* m0 = &sM[(c1b * 4 + 0) * DCv + c2b * 4];
        float* m1r = &sM[(c1b * 4 + 1) * DCv + c2b * 4];
        float* m2r = &sM[(c1b * 4 + 2) * DCv + c2b * 4];
        float* m3r = &sM[(c1b * 4 + 3) * DCv + c2b * 4];
        atomicAdd(m0 + 0, r0.x); atomicAdd(m0 + 1, r0.y);
        atomicAdd(m0 + 2, r0.z); atomicAdd(m0 + 3, r0.w);
        atomicAdd(m1r + 0, r1.x); atomicAdd(m1r + 1, r1.y);
        atomicAdd(m1r + 2, r1.z); atomicAdd(m1r + 3, r1.w);
        atomicAdd(m2r + 0, r2.x); atomicAdd(m2r + 1, r2.y);
        atomicAdd(m2r + 2, r2.z); atomicAdd(m2r + 3, r2.w);
        atomicAdd(m3r + 0, r3.x); atomicAdd(m3r + 1, r3.y);
        atomicAdd(m3r + 2, r3.z); atomicAdd(m3r + 3, r3.w);
    }
    __syncthreads();

    float4 mv = *(const float4*)&sM[tid * 4];
    *(float4*)&Mws[(size_t)bid * 1024 + tid * 4] = mv;
}

// ---------------------------------------------------------------------------
// K2: M = sum(Mpart)/sqrt(32); O = M q; mask; softmax over t; conv2 + residual
// grid: (b,f) = 512 blocks x 512 threads. ~6 KB LDS.
// (512,2): 2 waves/EU -> 2 blocks/CU -> 128-VGPR cap. (512,4) capped VGPRs at
// 64 and spilled ~600 MB of scratch traffic -> 253 us (round-2 post-mortem).
// ---------------------------------------------------------------------------
__global__ __launch_bounds__(512, 2)
void k2_attn_conv_out(const float* __restrict__ inp,
                      const float* __restrict__ Qws, const float* __restrict__ Mws,
                      const float* __restrict__ wp, const float* __restrict__ bp,
                      const float* __restrict__ g2, const float* __restrict__ be2,
                      const float* __restrict__ m2, const float* __restrict__ v2,
                      const float* __restrict__ a2,
                      float* __restrict__ out)
{
    __shared__ __align__(16) float sM[DCv * DCv];  // 4 KB
    __shared__ float sS2[Cv], sT2[Cv];
    __shared__ float sWred[8 * DCv];
    __shared__ float sMx[DCv], sRZ[DCv];

    const int tid = threadIdx.x;
    const int bf  = blockIdx.x;
    const int b   = bf >> 7;
    const int f   = bf & 127;

    const float INV = 0.17677669529663687f;  // 1/sqrt(32)
    const float* mp0 = Mws + (size_t)bf * 2048;
    const float* mp1 = mp0 + 1024;
    sM[tid]       = (mp0[tid]       + mp1[tid])       * INV;
    sM[tid + 512] = (mp0[tid + 512] + mp1[tid + 512]) * INV;
    if (tid < Cv) {
        float s = g2[tid] / sqrtf(v2[tid] + 1e-5f);
        sS2[tid] = s;
        sT2[tid] = (bp[tid] - m2[tid]) * s + be2[tid];
    }
    const float alpha2 = a2[0];
    __syncthreads();

    const int t = tid;
    const int l = tid & 63, w = tid >> 6;

    // q column from workspace (contiguous 128 B per thread)
    float q[DCv];
    const float* qg = Qws + ((size_t)bf * Tv + t) * DCv;
    #pragma unroll
    for (int j = 0; j < 8; ++j) {
        float4 v = *(const float4*)&qg[j * 4];
        q[4*j] = v.x; q[4*j+1] = v.y; q[4*j+2] = v.z; q[4*j+3] = v.w;
    }

    // O = M q (M rows broadcast from LDS); overwrite q in place to cut live regs
    float O[DCv];
    #pragma unroll 2
    for (int j = 0; j < 8; ++j) {
        const float4* M0 = (const float4*)&sM[(4*j+0) * DCv];
        const float4* M1 = (const float4*)&sM[(4*j+1) * DCv];
        const float4* M2 = (const float4*)&sM[(4*j+2) * DCv];
        const float4* M3 = (const float4*)&sM[(4*j+3) * DCv];
        float d0 = 0.f, d1 = 0.f, d2 = 0.f, d3 = 0.f;
        #pragma unroll
        for (int kk = 0; kk < 8; ++kk) {
            float4 a = M0[kk], bq = M1[kk], c = M2[kk], d = M3[kk];
            d0 = fmaf(a.x, q[4*kk], d0); d0 = fmaf(a.y, q[4*kk+1], d0);
            d0 = fmaf(a.z, q[4*kk+2], d0); d0 = fmaf(a.w, q[4*kk+3], d0);
            d1 = fmaf(bq.x, q[4*kk], d1); d1 = fmaf(bq.y, q[4*kk+1], d1);
            d1 = fmaf(bq.z, q[4*kk+2], d1); d1 = fmaf(bq.w, q[4*kk+3], d1);
            d2 = fmaf(c.x, q[4*kk], d2); d2 = fmaf(c.y, q[4*kk+1], d2);
            d2 = fmaf(c.z, q[4*kk+2], d2); d2 = fmaf(c.w, q[4*kk+3], d2);
            d3 = fmaf(d.x, q[4*kk], d3); d3 = fmaf(d.y, q[4*kk+1], d3);
            d3 = fmaf(d.z, q[4*kk+2], d3); d3 = fmaf(d.w, q[4*kk+3], d3);
        }
        O[4*j] = d0; O[4*j+1] = d1; O[4*j+2] = d2; O[4*j+3] = d3;
    }

    // causal mask: valid iff t < f + 385
    int limit = f + (Tv - Fv + 1);
    if (limit > Tv) limit = Tv;
    const bool valid = t < limit;

    // softmax pass 1: per-channel max over t (wave butterfly + cross-wave LDS)
    {
        float mine = -INFINITY;
        #pragma unroll
        for (int c = 0; c < DCv; ++c) {
            float m = valid ? O[c] : -INFINITY;
            #pragma unroll
            for (int s = 1; s < 64; s <<= 1) m = fmaxf(m, __shfl_xor(m, s));
            mine = ((l & 31) == c) ? m : mine;
        }
        if (l < DCv) sWred[w * DCv + l] = mine;
    }
    __syncthreads();
    if (tid < DCv) {
        float mx = sWred[tid];
        #pragma unroll
        for (int ww = 1; ww < 8; ++ww) mx = fmaxf(mx, sWred[ww * DCv + tid]);
        sMx[tid] = mx;
    }
    __syncthreads();

    // softmax pass 2: exp + per-channel sum (e overwrites O in place)
    #pragma unroll
    for (int c = 0; c < DCv; ++c) O[c] = valid ? __expf(O[c] - sMx[c]) : 0.f;
    {
        float mine = 0.f;
        #pragma unroll
        for (int c = 0; c < DCv; ++c) {
            float s2 = O[c];
            #pragma unroll
            for (int s = 1; s < 64; s <<= 1) s2 += __shfl_xor(s2, s);
            mine = ((l & 31) == c) ? s2 : mine;
        }
        if (l < DCv) sWred[w * DCv + l] = mine;
    }
    __syncthreads();
    if (tid < DCv) {
        float z = sWred[tid];
        #pragma unroll
        for (int ww = 1; ww < 8; ++ww) z += sWred[ww * DCv + tid];
        sRZ[tid] = 1.f / z;
    }
    __syncthreads();
    #pragma unroll
    for (int c = 0; c < DCv; ++c) O[c] *= sRZ[c];

    // conv2 + BN + PReLU + residual
    #pragma unroll
    for (int half = 0; half < 2; ++half) {
        const float* pin = inp + ((size_t)(b * Cv + half * 32) * Fv + f) * Tv + t;
        float*       pot = out + ((size_t)(b * Cv + half * 32) * Fv + f) * Tv + t;
        #pragma unroll 4
        for (int oo = 0; oo < 32; ++oo) {
            const int o = half * 32 + oo;
            const float* wr = wp + o * DCv;  // uniform -> scalar loads
            float a = 0.f;
            #pragma unroll
            for (int c2 = 0; c2 < DCv; ++c2) a = fmaf(wr[c2], O[c2], a);
            float z = fmaf(a, sS2[o], sT2[o]);
            z = z >= 0.f ? z : alpha2 * z;
            pot[oo * FT] = z + pin[oo * FT];
        }
    }
}

extern "C" void kernel_launch(void* const* d_in, const int* in_sizes, int n_in,
                              void* d_out, int out_size, void* d_ws, size_t ws_size,
                              hipStream_t stream) {
    const float* inp = (const float*)d_in[0];
    const float* w1  = (const float*)d_in[1];
    const float* b1  = (const float*)d_in[2];
    const float* g1  = (const float*)d_in[3];
    const float* be1 = (const float*)d_in[4];
    const float* m1  = (const float*)d_in[5];
    const float* v1  = (const float*)d_in[6];
    const float* a1  = (const float*)d_in[7];
    const float* wp  = (const float*)d_in[8];
    const float* bp  = (const float*)d_in[9];
    const float* g2  = (const float*)d_in[10];
    const float* be2 = (const float*)d_in[11];
    const float* m2  = (const float*)d_in[12];
    const float* v2  = (const float*)d_in[13];
    const float* a2  = (const float*)d_in[14];

    float* Qws = (float*)d_ws;                                  // 4*128*512*32 f32 = 33.6 MB
    float* Mws = Qws + (size_t)Bv * Fv * Tv * DCv;              // 1024*1024 f32 = 4.2 MB

    k1_conv_q_m<<<dim3(Bv * Fv * 2), dim3(256), 0, stream>>>(
        inp, w1, b1, g1, be1, m1, v1, a1, Qws, Mws);
    k2_attn_conv_out<<<dim3(Bv * Fv), dim3(512), 0, stream>>>(
        inp, Qws, Mws, wp, bp, g2, be2, m2, v2, a2, (float*)d_out);
}